// Round 4
// baseline (62.434 us; speedup 1.0000x reference)
//
#include <hip/hip_runtime.h>
#include <math.h>

#define BB 4
#define NQ 256
#define NK 1024
#define DD 256
#define HH 256

// ---------------- K1: Projection GEMM (fp32) + E=exp(2x) epilogue ----------
// E[m,h] = exp(2*clamp(sum_d A[m,d]*W[d,h], -8, 8)).
// tanh(z) = 1 - 2/(1+e^{2z}) is applied implicitly downstream.
// K-tiles whose rows are all masked (local row >= valid_len) exit early.
#define TM 64
#define TN 64
#define TKK 16
#define NT (DD / TKK)   // 16 k-steps

__global__ __launch_bounds__(256) void proj_exp_kernel(
    const float* __restrict__ Q, const float* __restrict__ K,
    const float* __restrict__ Wq, const float* __restrict__ Wk,
    const int* __restrict__ vlen,
    float* __restrict__ Eq, float* __restrict__ Ek)
{
    const int QTILES = (BB * NQ) / TM;   // 16
    int bx = blockIdx.x;
    const float* A; const float* W; float* C; int bm;
    if (bx < QTILES) { A = Q; W = Wq; C = Eq; bm = bx * TM; }
    else {
        int kt = bx - QTILES;            // 0..63, 16 tiles per batch
        int b = kt >> 4;
        int lr = (kt & 15) * TM;         // batch-local row start
        if (lr >= vlen[b]) return;       // fully masked K-tile: skip
        A = K; W = Wk; C = Ek; bm = kt * TM;
    }
    int bn = blockIdx.y * TN;

    __shared__ float As[2][TKK][TM + 4];
    __shared__ float Ws[2][TKK][TN + 4];

    int tid = threadIdx.x;
    int ar = tid >> 2, ac4 = tid & 3;
    int wkk = tid >> 4, wc4 = tid & 15;
    int ty = tid >> 4, tx = tid & 15;

    float4 aR = *(const float4*)&A[(size_t)(bm + ar) * DD + ac4 * 4];
    float4 wR = *(const float4*)&W[(size_t)wkk * HH + bn + wc4 * 4];

    float acc[4][4] = {};

    for (int t = 0; t < NT; ++t) {
        int cur = t & 1;
        As[cur][ac4 * 4 + 0][ar] = aR.x;
        As[cur][ac4 * 4 + 1][ar] = aR.y;
        As[cur][ac4 * 4 + 2][ar] = aR.z;
        As[cur][ac4 * 4 + 3][ar] = aR.w;
        *(float4*)&Ws[cur][wkk][wc4 * 4] = wR;
        if (t + 1 < NT) {
            int k0 = (t + 1) * TKK;
            aR = *(const float4*)&A[(size_t)(bm + ar) * DD + k0 + ac4 * 4];
            wR = *(const float4*)&W[(size_t)(k0 + wkk) * HH + bn + wc4 * 4];
        }
        __syncthreads();
#pragma unroll
        for (int kk = 0; kk < TKK; ++kk) {
            float4 a4 = *(const float4*)&As[cur][kk][ty * 4];
            float4 w4 = *(const float4*)&Ws[cur][kk][tx * 4];
            acc[0][0] = fmaf(a4.x, w4.x, acc[0][0]);
            acc[0][1] = fmaf(a4.x, w4.y, acc[0][1]);
            acc[0][2] = fmaf(a4.x, w4.z, acc[0][2]);
            acc[0][3] = fmaf(a4.x, w4.w, acc[0][3]);
            acc[1][0] = fmaf(a4.y, w4.x, acc[1][0]);
            acc[1][1] = fmaf(a4.y, w4.y, acc[1][1]);
            acc[1][2] = fmaf(a4.y, w4.z, acc[1][2]);
            acc[1][3] = fmaf(a4.y, w4.w, acc[1][3]);
            acc[2][0] = fmaf(a4.z, w4.x, acc[2][0]);
            acc[2][1] = fmaf(a4.z, w4.y, acc[2][1]);
            acc[2][2] = fmaf(a4.z, w4.z, acc[2][2]);
            acc[2][3] = fmaf(a4.z, w4.w, acc[2][3]);
            acc[3][0] = fmaf(a4.w, w4.x, acc[3][0]);
            acc[3][1] = fmaf(a4.w, w4.y, acc[3][1]);
            acc[3][2] = fmaf(a4.w, w4.z, acc[3][2]);
            acc[3][3] = fmaf(a4.w, w4.w, acc[3][3]);
        }
        __syncthreads();
    }

#pragma unroll
    for (int i = 0; i < 4; ++i) {
        int m = bm + ty * 4 + i;
        float4 o;
        // clamp +-8: |tanh| error < 2.4e-7, keeps E and quad-products finite
        o.x = __expf(2.f * fminf(fmaxf(acc[i][0], -8.f), 8.f));
        o.y = __expf(2.f * fminf(fmaxf(acc[i][1], -8.f), 8.f));
        o.z = __expf(2.f * fminf(fmaxf(acc[i][2], -8.f), 8.f));
        o.w = __expf(2.f * fminf(fmaxf(acc[i][3], -8.f), 8.f));
        *(float4*)&C[(size_t)m * HH + bn + tx * 4] = o;
    }
}

// ---------------- K2: T-partials --------------------------------------------
// T(q,k) = sum_h w_h/(1+Eq_h*Ek_h); logit = -2T (the sum_h w_h constant
// cancels in softmax). Block = (b, 64q, 64k, 64h-chunk); 4x4 micro, strided
// rows (1-row lane stride -> 2-way bank alias = free). Quad-batched rational
// sum: one v_rcp per 4 h-terms.
#define SH 64   // h-chunk
#define NHC (HH / SH)   // 4

__global__ __launch_bounds__(256) void scores_kernel(
    const float* __restrict__ Eq, const float* __restrict__ Ek,
    const float* __restrict__ wv, const int* __restrict__ vlen,
    float* __restrict__ Tpart)
{
    __shared__ __align__(16) float sQ[64][SH + 4];
    __shared__ __align__(16) float sK[64][SH + 4];
    __shared__ float sW[SH];

    int bid = blockIdx.x;
    int b  = bid & 3;
    int qc = (bid >> 2) & 3;
    int kc = (bid >> 4) & 15;
    int hc = bid >> 8;
    int L = vlen[b];
    int k0 = kc * 64;
    if (k0 >= L) return;                 // masked chunk: uniform exit
    int q0 = qc * 64, h0 = hc * SH;

    int tid = threadIdx.x;
    {
        int rr0 = tid >> 4;              // 0..15
        int c4  = tid & 15;              // f4 col 0..15
        const float* gq = Eq + ((size_t)b * NQ + q0) * HH + h0;
        const float* gk = Ek + ((size_t)b * NK + k0) * HH + h0;
#pragma unroll
        for (int rr = 0; rr < 4; ++rr) {
            int r = rr0 + rr * 16;
            *(float4*)&sQ[r][c4 * 4] = *(const float4*)&gq[(size_t)r * HH + c4 * 4];
            *(float4*)&sK[r][c4 * 4] = *(const float4*)&gk[(size_t)r * HH + c4 * 4];
        }
        if (tid < SH) sW[tid] = wv[h0 + tid];
    }
    __syncthreads();

    int qi = tid >> 4, ki = tid & 15;
    float acc[4][4] = {};

    for (int h4 = 0; h4 < SH / 4; ++h4) {
        float4 w = *(const float4*)&sW[h4 * 4];
        float wxy = w.x + w.y, wzw = w.z + w.w;
        float4 Aq[4], Bk[4];
#pragma unroll
        for (int i = 0; i < 4; ++i) Aq[i] = *(const float4*)&sQ[qi + 16 * i][h4 * 4];
#pragma unroll
        for (int j = 0; j < 4; ++j) Bk[j] = *(const float4*)&sK[ki + 16 * j][h4 * 4];
#pragma unroll
        for (int i = 0; i < 4; ++i)
#pragma unroll
            for (int j = 0; j < 4; ++j) {
                float4 a = Aq[i], e = Bk[j];
                float E1 = a.x * e.x, E2 = a.y * e.y;
                float E3 = a.z * e.z, E4 = a.w * e.w;
                float d1 = E1 + 1.f, d2 = E2 + 1.f;
                float d3 = E3 + 1.f, d4 = E4 + 1.f;
                // w1/(1+E1)+w2/(1+E2) = n12/d12
                float n12 = fmaf(w.x, E2, fmaf(w.y, E1, wxy));
                float n34 = fmaf(w.z, E4, fmaf(w.w, E3, wzw));
                float d12 = d1 * d2, d34 = d3 * d4;
                float num = fmaf(n12, d34, n34 * d12);
                acc[i][j] = fmaf(num, __builtin_amdgcn_rcpf(d12 * d34), acc[i][j]);
            }
    }

    float* Tb = Tpart + (size_t)hc * (BB * NQ * NK)
              + ((size_t)b * NQ + q0) * NK + k0;
#pragma unroll
    for (int i = 0; i < 4; ++i)
#pragma unroll
        for (int j = 0; j < 4; ++j)
            Tb[(size_t)(qi + 16 * i) * NK + ki + 16 * j] = acc[i][j];
}

// ---------------- K3: combine partials -> P = exp(-2T), row sums ------------
__global__ __launch_bounds__(256) void combine_kernel(
    const float* __restrict__ Tpart, const int* __restrict__ vlen,
    float* __restrict__ P, float* __restrict__ Psum)
{
    __shared__ float sRed[4];
    int row = blockIdx.x;                // b*NQ + q, 1024 rows
    int b = row >> 8;
    int L = vlen[b];
    int tid = threadIdx.x;
    const size_t stride = (size_t)BB * NQ * NK;
    const float* T0 = Tpart + (size_t)row * NK;

    int k = tid * 4;
    float4 p = {0.f, 0.f, 0.f, 0.f};
    if (k < L) {      // f4 is 64-chunk-local: all 4 lanes' T written if k<L
        float4 t0 = *(const float4*)&T0[k];
        float4 t1 = *(const float4*)&T0[stride + k];
        float4 t2 = *(const float4*)&T0[2 * stride + k];
        float4 t3 = *(const float4*)&T0[3 * stride + k];
        float Tx = (t0.x + t1.x) + (t2.x + t3.x);
        float Ty = (t0.y + t1.y) + (t2.y + t3.y);
        float Tz = (t0.z + t1.z) + (t2.z + t3.z);
        float Tw = (t0.w + t1.w) + (t2.w + t3.w);
        p.x = __expf(-2.f * Tx);
        p.y = (k + 1 < L) ? __expf(-2.f * Ty) : 0.f;
        p.z = (k + 2 < L) ? __expf(-2.f * Tz) : 0.f;
        p.w = (k + 3 < L) ? __expf(-2.f * Tw) : 0.f;
    }
    *(float4*)&P[(size_t)row * NK + k] = p;

    float s = (p.x + p.y) + (p.z + p.w);
#pragma unroll
    for (int o = 32; o; o >>= 1) s += __shfl_xor(s, o, 64);
    if ((tid & 63) == 0) sRed[tid >> 6] = s;
    __syncthreads();
    if (tid == 0) Psum[row] = (sRed[0] + sRed[1]) + (sRed[2] + sRed[3]);
}

// ---------------- K4: PV GEMM + normalize ----------------
// 32q x 32d per block, 4x4 micro, 4-way k-split across waves, register-staged
// double buffering. out = (P @ V) / Psum[row]. P rows are fully written
// (zeros beyond L) so no tail guards needed.
__global__ __launch_bounds__(256) void pv_kernel(
    const float* __restrict__ P, const float* __restrict__ V,
    const float* __restrict__ Psum, const int* __restrict__ vlen,
    float* __restrict__ out)
{
    __shared__ __align__(16) float sPt[2][32][36];   // [k][q]
    __shared__ __align__(16) float sV[2][32][36];    // [k][d]
    __shared__ float sAll[3][64][17];

    int bid = blockIdx.x;
    int b = bid & 3;
    int rest = bid >> 2;
    int qt = rest >> 3, dt = rest & 7;
    int q0 = qt * 32, d0 = dt * 32;
    int L = vlen[b];
    int nc = (L + 31) >> 5;

    int tid = threadIdx.x;
    int r = tid >> 3, c4 = tid & 7;
    int w = tid >> 6, sp = tid & 63;
    int qg = sp >> 3, dg = sp & 7;

    const float* Pb = P + ((size_t)b * NQ + q0 + r) * NK;
    const float* Vb = V + (size_t)b * NK * DD + d0;

    float4 pf = *(const float4*)(Pb + c4 * 4);
    float4 vf = *(const float4*)(Vb + (size_t)r * DD + c4 * 4);

    float acc[4][4] = {};

    for (int c = 0; c < nc; ++c) {
        int cur = c & 1;
        sPt[cur][c4 * 4 + 0][r] = pf.x;
        sPt[cur][c4 * 4 + 1][r] = pf.y;
        sPt[cur][c4 * 4 + 2][r] = pf.z;
        sPt[cur][c4 * 4 + 3][r] = pf.w;
        *(float4*)&sV[cur][r][c4 * 4] = vf;
        if (c + 1 < nc) {
            int kn = (c + 1) * 32;
            pf = *(const float4*)(Pb + kn + c4 * 4);
            vf = *(const float4*)(Vb + (size_t)(kn + r) * DD + c4 * 4);
        }
        __syncthreads();
#pragma unroll
        for (int kk = 0; kk < 8; ++kk) {
            float4 A  = *(const float4*)&sPt[cur][w * 8 + kk][qg * 4];
            float4 Bv = *(const float4*)&sV[cur][w * 8 + kk][dg * 4];
            acc[0][0] = fmaf(A.x, Bv.x, acc[0][0]);
            acc[0][1] = fmaf(A.x, Bv.y, acc[0][1]);
            acc[0][2] = fmaf(A.x, Bv.z, acc[0][2]);
            acc[0][3] = fmaf(A.x, Bv.w, acc[0][3]);
            acc[1][0] = fmaf(A.y, Bv.x, acc[1][0]);
            acc[1][1] = fmaf(A.y, Bv.y, acc[1][1]);
            acc[1][2] = fmaf(A.y, Bv.z, acc[1][2]);
            acc[1][3] = fmaf(A.y, Bv.w, acc[1][3]);
            acc[2][0] = fmaf(A.z, Bv.x, acc[2][0]);
            acc[2][1] = fmaf(A.z, Bv.y, acc[2][1]);
            acc[2][2] = fmaf(A.z, Bv.z, acc[2][2]);
            acc[2][3] = fmaf(A.z, Bv.w, acc[2][3]);
            acc[3][0] = fmaf(A.w, Bv.x, acc[3][0]);
            acc[3][1] = fmaf(A.w, Bv.y, acc[3][1]);
            acc[3][2] = fmaf(A.w, Bv.z, acc[3][2]);
            acc[3][3] = fmaf(A.w, Bv.w, acc[3][3]);
        }
        __syncthreads();
    }

    if (w > 0) {
#pragma unroll
        for (int i = 0; i < 4; ++i)
#pragma unroll
            for (int j = 0; j < 4; ++j) sAll[w - 1][sp][i * 4 + j] = acc[i][j];
    }
    __syncthreads();
    if (w == 0) {
#pragma unroll
        for (int ww = 0; ww < 3; ++ww)
#pragma unroll
            for (int i = 0; i < 4; ++i)
#pragma unroll
                for (int j = 0; j < 4; ++j) acc[i][j] += sAll[ww][sp][i * 4 + j];
#pragma unroll
        for (int i = 0; i < 4; ++i) {
            float inv = 1.0f / Psum[(size_t)b * NQ + q0 + qg * 4 + i];
            float4 o = { acc[i][0] * inv, acc[i][1] * inv,
                         acc[i][2] * inv, acc[i][3] * inv };
            *(float4*)&out[((size_t)b * NQ + q0 + qg * 4 + i) * DD + d0 + dg * 4] = o;
        }
    }
}

extern "C" void kernel_launch(void* const* d_in, const int* in_sizes, int n_in,
                              void* d_out, int out_size, void* d_ws, size_t ws_size,
                              hipStream_t stream) {
    const float* queries = (const float*)d_in[0];  // [B,NQ,D]
    const float* keys    = (const float*)d_in[1];  // [B,NK,D]
    const float* values  = (const float*)d_in[2];  // [B,NK,D]
    const int*   vlens   = (const int*)d_in[3];    // [B]
    const float* Wq      = (const float*)d_in[4];  // [D,H]
    const float* Wk      = (const float*)d_in[5];  // [D,H]
    const float* wv      = (const float*)d_in[6];  // [H]
    float* out = (float*)d_out;

    float* Eqb   = (float*)d_ws;                          // 1 MB
    float* Ekb   = Eqb + (size_t)BB * NQ * HH;            // 4 MB
    float* Tpart = Ekb + (size_t)BB * NK * HH;            // 16 MB (4 partials)
    float* P     = Tpart + (size_t)NHC * BB * NQ * NK;    // 4 MB
    float* Psum  = P + (size_t)BB * NQ * NK;              // 4 KB

    dim3 pgrid((BB * NQ) / TM + (BB * NK) / TM, HH / TN);   // (80,4)
    proj_exp_kernel<<<pgrid, 256, 0, stream>>>(queries, keys, Wq, Wk, vlens,
                                               Eqb, Ekb);

    scores_kernel<<<dim3(4 * 4 * 16 * NHC), 256, 0, stream>>>(
        Eqb, Ekb, wv, vlens, Tpart);

    combine_kernel<<<dim3(BB * NQ), 256, 0, stream>>>(Tpart, vlens, P, Psum);

    pv_kernel<<<dim3(BB * (NQ / 32) * (DD / 32)), 256, 0, stream>>>(
        P, values, Psum, vlens, out);
}

// Round 5
// 56.137 us; speedup vs baseline: 1.1122x; 1.1122x over previous
//
#include <hip/hip_runtime.h>
#include <math.h>

#define BB 4
#define NQ 256
#define NK 1024
#define DD 256
#define HH 256

// ---------------- K1: Projection GEMM (fp32) + E=exp(2x) epilogue ----------
// E[m,h] = exp(2*clamp(sum_d A[m,d]*W[d,h], -8, 8)).
// tanh(z) = 1 - 2/(1+e^{2z}) applied implicitly downstream; sum_h w_h const
// cancels in softmax. Fully-masked K-tiles exit early.
#define TM 64
#define TN 64
#define TKK 16
#define NT (DD / TKK)   // 16 k-steps

__global__ __launch_bounds__(256) void proj_exp_kernel(
    const float* __restrict__ Q, const float* __restrict__ K,
    const float* __restrict__ Wq, const float* __restrict__ Wk,
    const int* __restrict__ vlen,
    float* __restrict__ Eq, float* __restrict__ Ek)
{
    const int QTILES = (BB * NQ) / TM;   // 16
    int bx = blockIdx.x;
    const float* A; const float* W; float* C; int bm;
    if (bx < QTILES) { A = Q; W = Wq; C = Eq; bm = bx * TM; }
    else {
        int kt = bx - QTILES;            // 0..63
        int b = kt >> 4;
        int lr = (kt & 15) * TM;         // batch-local row start
        if (lr >= vlen[b]) return;       // fully masked K-tile: skip
        A = K; W = Wk; C = Ek; bm = kt * TM;
    }
    int bn = blockIdx.y * TN;

    __shared__ float As[2][TKK][TM + 4];
    __shared__ float Ws[2][TKK][TN + 4];

    int tid = threadIdx.x;
    int ar = tid >> 2, ac4 = tid & 3;
    int wkk = tid >> 4, wc4 = tid & 15;
    int ty = tid >> 4, tx = tid & 15;

    float4 aR = *(const float4*)&A[(size_t)(bm + ar) * DD + ac4 * 4];
    float4 wR = *(const float4*)&W[(size_t)wkk * HH + bn + wc4 * 4];

    float acc[4][4] = {};

    for (int t = 0; t < NT; ++t) {
        int cur = t & 1;
        As[cur][ac4 * 4 + 0][ar] = aR.x;
        As[cur][ac4 * 4 + 1][ar] = aR.y;
        As[cur][ac4 * 4 + 2][ar] = aR.z;
        As[cur][ac4 * 4 + 3][ar] = aR.w;
        *(float4*)&Ws[cur][wkk][wc4 * 4] = wR;
        if (t + 1 < NT) {
            int k0 = (t + 1) * TKK;
            aR = *(const float4*)&A[(size_t)(bm + ar) * DD + k0 + ac4 * 4];
            wR = *(const float4*)&W[(size_t)(k0 + wkk) * HH + bn + wc4 * 4];
        }
        __syncthreads();
#pragma unroll
        for (int kk = 0; kk < TKK; ++kk) {
            float4 a4 = *(const float4*)&As[cur][kk][ty * 4];
            float4 w4 = *(const float4*)&Ws[cur][kk][tx * 4];
            acc[0][0] = fmaf(a4.x, w4.x, acc[0][0]);
            acc[0][1] = fmaf(a4.x, w4.y, acc[0][1]);
            acc[0][2] = fmaf(a4.x, w4.z, acc[0][2]);
            acc[0][3] = fmaf(a4.x, w4.w, acc[0][3]);
            acc[1][0] = fmaf(a4.y, w4.x, acc[1][0]);
            acc[1][1] = fmaf(a4.y, w4.y, acc[1][1]);
            acc[1][2] = fmaf(a4.y, w4.z, acc[1][2]);
            acc[1][3] = fmaf(a4.y, w4.w, acc[1][3]);
            acc[2][0] = fmaf(a4.z, w4.x, acc[2][0]);
            acc[2][1] = fmaf(a4.z, w4.y, acc[2][1]);
            acc[2][2] = fmaf(a4.z, w4.z, acc[2][2]);
            acc[2][3] = fmaf(a4.z, w4.w, acc[2][3]);
            acc[3][0] = fmaf(a4.w, w4.x, acc[3][0]);
            acc[3][1] = fmaf(a4.w, w4.y, acc[3][1]);
            acc[3][2] = fmaf(a4.w, w4.z, acc[3][2]);
            acc[3][3] = fmaf(a4.w, w4.w, acc[3][3]);
        }
        __syncthreads();
    }

#pragma unroll
    for (int i = 0; i < 4; ++i) {
        int m = bm + ty * 4 + i;
        float4 o;
        // clamp +-8: |tanh| error < 2.4e-7, keeps E and quad-products finite
        o.x = __expf(2.f * fminf(fmaxf(acc[i][0], -8.f), 8.f));
        o.y = __expf(2.f * fminf(fmaxf(acc[i][1], -8.f), 8.f));
        o.z = __expf(2.f * fminf(fmaxf(acc[i][2], -8.f), 8.f));
        o.w = __expf(2.f * fminf(fmaxf(acc[i][3], -8.f), 8.f));
        *(float4*)&C[(size_t)m * HH + bn + tx * 4] = o;
    }
}

// ---------------- K2: scores -> P = exp(-2T) + per-chunk row sums -----------
// T(q,k) = sum_h w_h/(1+Eq_h*Ek_h); logit = -2T (sum_h w_h cancels in
// softmax). One pass over full H per 32x32 tile. Quad-batched rational sum:
// one v_rcp per 4 h-terms. Masked k -> P = 0. Deterministic Psum via shfl.
__global__ __launch_bounds__(256) void scores_kernel(
    const float* __restrict__ Eq, const float* __restrict__ Ek,
    const float* __restrict__ wv, const int* __restrict__ vlen,
    float* __restrict__ P, float* __restrict__ Psum)
{
    __shared__ __align__(16) float sQ[32][HH + 4];
    __shared__ __align__(16) float sK[32][HH + 4];
    __shared__ __align__(16) float sW[HH];

    int bid = blockIdx.x;
    int b = bid & 3;                 // batch-interleaved for balance
    int rest = bid >> 2;
    int qc = rest & 7;               // 8 q-chunks of 32
    int kc = rest >> 3;              // 32 k-chunks of 32
    int L = vlen[b];
    int k0 = kc * 32;
    if (k0 >= L) return;             // fully masked chunk: uniform exit
    int q0 = qc * 32;

    int tid = threadIdx.x;
    {
        int c4 = tid & 63, r0 = tid >> 6;
        const float4* gq = (const float4*)(Eq + ((size_t)b * NQ + q0) * HH);
        const float4* gk = (const float4*)(Ek + ((size_t)b * NK + k0) * HH);
#pragma unroll
        for (int r = 0; r < 32; r += 4) {
            *(float4*)&sQ[r + r0][c4 * 4] = gq[(size_t)(r + r0) * (HH / 4) + c4];
            *(float4*)&sK[r + r0][c4 * 4] = gk[(size_t)(r + r0) * (HH / 4) + c4];
        }
        sW[tid] = wv[tid];
    }
    __syncthreads();

    int ki = tid & 15, qi = tid >> 4;
    float a00 = 0.f, a01 = 0.f, a10 = 0.f, a11 = 0.f;
    const float4* qp0 = (const float4*)&sQ[qi][0];
    const float4* qp1 = (const float4*)&sQ[qi + 16][0];
    const float4* kp0 = (const float4*)&sK[ki][0];
    const float4* kp1 = (const float4*)&sK[ki + 16][0];
    const float4* wp  = (const float4*)sW;

#pragma unroll 4
    for (int h4 = 0; h4 < HH / 4; ++h4) {
        float4 w = wp[h4];
        float wxy = w.x + w.y, wzw = w.z + w.w;
        float4 A0 = qp0[h4], A1 = qp1[h4];
        float4 B0 = kp0[h4], B1 = kp1[h4];
#define QUAD(acc, Aq, Bk)                                                    \
        {                                                                    \
            float E1 = Aq.x * Bk.x, E2 = Aq.y * Bk.y;                        \
            float E3 = Aq.z * Bk.z, E4 = Aq.w * Bk.w;                        \
            float d1 = E1 + 1.f, d2 = E2 + 1.f;                              \
            float d3 = E3 + 1.f, d4 = E4 + 1.f;                              \
            float n12 = fmaf(w.x, E2, fmaf(w.y, E1, wxy));                   \
            float n34 = fmaf(w.z, E4, fmaf(w.w, E3, wzw));                   \
            float d12 = d1 * d2, d34 = d3 * d4;                              \
            float num = fmaf(n12, d34, n34 * d12);                           \
            acc = fmaf(num, __builtin_amdgcn_rcpf(d12 * d34), acc);          \
        }
        QUAD(a00, A0, B0);
        QUAD(a01, A0, B1);
        QUAD(a10, A1, B0);
        QUAD(a11, A1, B1);
#undef QUAD
    }

    int kA = k0 + ki, kB = kA + 16;
    float p00 = (kA < L) ? __expf(-2.f * a00) : 0.f;
    float p10 = (kA < L) ? __expf(-2.f * a10) : 0.f;
    float p01 = (kB < L) ? __expf(-2.f * a01) : 0.f;
    float p11 = (kB < L) ? __expf(-2.f * a11) : 0.f;

    float* s0 = P + ((size_t)b * NQ + q0 + qi) * NK;
    float* s1 = P + ((size_t)b * NQ + q0 + qi + 16) * NK;
    s0[kA] = p00; s0[kB] = p01;
    s1[kA] = p10; s1[kB] = p11;

    // deterministic per-chunk row sums (reduce over ki = low 4 lane bits)
    float r0s = p00 + p01, r1s = p10 + p11;
#pragma unroll
    for (int o = 1; o <= 8; o <<= 1) {
        r0s += __shfl_xor(r0s, o, 64);
        r1s += __shfl_xor(r1s, o, 64);
    }
    if (ki == 0) {
        Psum[((size_t)b * NQ + q0 + qi) * 32 + kc] = r0s;
        Psum[((size_t)b * NQ + q0 + qi + 16) * 32 + kc] = r1s;
    }
}

// ---------------- K3: PV GEMM + normalize ----------------
// 32q x 32d per block, 4x4 micro, 4-way k-split across waves, register-staged
// double buffering. out = (P @ V) / rowsum. P rows fully written for k<L
// chunks (zeros in tails), so only chunk count depends on L.
__global__ __launch_bounds__(256) void pv_kernel(
    const float* __restrict__ P, const float* __restrict__ V,
    const float* __restrict__ Psum, const int* __restrict__ vlen,
    float* __restrict__ out)
{
    __shared__ __align__(16) float sPt[2][32][36];   // [k][q]
    __shared__ __align__(16) float sV[2][32][36];    // [k][d]
    __shared__ float sAll[3][64][17];
    __shared__ float sRowsum[32];

    int bid = blockIdx.x;
    int b = bid & 3;
    int rest = bid >> 2;
    int qt = rest >> 3, dt = rest & 7;
    int q0 = qt * 32, d0 = dt * 32;
    int L = vlen[b];
    int nc = (L + 31) >> 5;

    int tid = threadIdx.x;
    if (tid < 32) {
        float s = 0.f;
        const float* pp = Psum + ((size_t)b * NQ + q0 + tid) * 32;
        for (int c = 0; c < nc; ++c) s += pp[c];
        sRowsum[tid] = s;
    }

    int r = tid >> 3, c4 = tid & 7;
    int w = tid >> 6, sp = tid & 63;
    int qg = sp >> 3, dg = sp & 7;

    const float* Pb = P + ((size_t)b * NQ + q0 + r) * NK;
    const float* Vb = V + (size_t)b * NK * DD + d0;

    float4 pf = *(const float4*)(Pb + c4 * 4);
    float4 vf = *(const float4*)(Vb + (size_t)r * DD + c4 * 4);

    float acc[4][4] = {};

    for (int c = 0; c < nc; ++c) {
        int cur = c & 1;
        sPt[cur][c4 * 4 + 0][r] = pf.x;
        sPt[cur][c4 * 4 + 1][r] = pf.y;
        sPt[cur][c4 * 4 + 2][r] = pf.z;
        sPt[cur][c4 * 4 + 3][r] = pf.w;
        *(float4*)&sV[cur][r][c4 * 4] = vf;
        if (c + 1 < nc) {
            int kn = (c + 1) * 32;
            pf = *(const float4*)(Pb + kn + c4 * 4);
            vf = *(const float4*)(Vb + (size_t)(kn + r) * DD + c4 * 4);
        }
        __syncthreads();
#pragma unroll
        for (int kk = 0; kk < 8; ++kk) {
            float4 A  = *(const float4*)&sPt[cur][w * 8 + kk][qg * 4];
            float4 Bv = *(const float4*)&sV[cur][w * 8 + kk][dg * 4];
            acc[0][0] = fmaf(A.x, Bv.x, acc[0][0]);
            acc[0][1] = fmaf(A.x, Bv.y, acc[0][1]);
            acc[0][2] = fmaf(A.x, Bv.z, acc[0][2]);
            acc[0][3] = fmaf(A.x, Bv.w, acc[0][3]);
            acc[1][0] = fmaf(A.y, Bv.x, acc[1][0]);
            acc[1][1] = fmaf(A.y, Bv.y, acc[1][1]);
            acc[1][2] = fmaf(A.y, Bv.z, acc[1][2]);
            acc[1][3] = fmaf(A.y, Bv.w, acc[1][3]);
            acc[2][0] = fmaf(A.z, Bv.x, acc[2][0]);
            acc[2][1] = fmaf(A.z, Bv.y, acc[2][1]);
            acc[2][2] = fmaf(A.z, Bv.z, acc[2][2]);
            acc[2][3] = fmaf(A.z, Bv.w, acc[2][3]);
            acc[3][0] = fmaf(A.w, Bv.x, acc[3][0]);
            acc[3][1] = fmaf(A.w, Bv.y, acc[3][1]);
            acc[3][2] = fmaf(A.w, Bv.z, acc[3][2]);
            acc[3][3] = fmaf(A.w, Bv.w, acc[3][3]);
        }
        __syncthreads();
    }

    if (w > 0) {
#pragma unroll
        for (int i = 0; i < 4; ++i)
#pragma unroll
            for (int j = 0; j < 4; ++j) sAll[w - 1][sp][i * 4 + j] = acc[i][j];
    }
    __syncthreads();
    if (w == 0) {
#pragma unroll
        for (int ww = 0; ww < 3; ++ww)
#pragma unroll
            for (int i = 0; i < 4; ++i)
#pragma unroll
                for (int j = 0; j < 4; ++j) acc[i][j] += sAll[ww][sp][i * 4 + j];
#pragma unroll
        for (int i = 0; i < 4; ++i) {
            float inv = 1.0f / sRowsum[qg * 4 + i];
            float4 o = { acc[i][0] * inv, acc[i][1] * inv,
                         acc[i][2] * inv, acc[i][3] * inv };
            *(float4*)&out[((size_t)b * NQ + q0 + qg * 4 + i) * DD + d0 + dg * 4] = o;
        }
    }
}

extern "C" void kernel_launch(void* const* d_in, const int* in_sizes, int n_in,
                              void* d_out, int out_size, void* d_ws, size_t ws_size,
                              hipStream_t stream) {
    const float* queries = (const float*)d_in[0];  // [B,NQ,D]
    const float* keys    = (const float*)d_in[1];  // [B,NK,D]
    const float* values  = (const float*)d_in[2];  // [B,NK,D]
    const int*   vlens   = (const int*)d_in[3];    // [B]
    const float* Wq      = (const float*)d_in[4];  // [D,H]
    const float* Wk      = (const float*)d_in[5];  // [D,H]
    const float* wv      = (const float*)d_in[6];  // [H]
    float* out = (float*)d_out;

    float* Eqb  = (float*)d_ws;                          // 1 MB
    float* Ekb  = Eqb + (size_t)BB * NQ * HH;            // 4 MB
    float* P    = Ekb + (size_t)BB * NK * HH;            // 4 MB
    float* Psum = P + (size_t)BB * NQ * NK;              // 128 KB [b][q][32]

    dim3 pgrid((BB * NQ) / TM + (BB * NK) / TM, HH / TN);   // (80,4)
    proj_exp_kernel<<<pgrid, 256, 0, stream>>>(queries, keys, Wq, Wk, vlens,
                                               Eqb, Ekb);

    scores_kernel<<<dim3(BB * (NQ / 32) * (NK / 32)), 256, 0, stream>>>(
        Eqb, Ekb, wv, vlens, P, Psum);

    pv_kernel<<<dim3(BB * (NQ / 32) * (DD / 32)), 256, 0, stream>>>(
        P, values, Psum, vlens, out);
}